// Round 1
// baseline (469.162 us; speedup 1.0000x reference)
//
#include <hip/hip_runtime.h>
#include <hip/hip_bf16.h>
#include <math.h>

#define T_TOK 32768
#define D_DIM 512
#define E_EXP 16
#define F_DIM 1024
#define C_CAP 2048

typedef __attribute__((ext_vector_type(8))) __bf16 bf16x8;
typedef __attribute__((ext_vector_type(4))) float f32x4;

__device__ __forceinline__ unsigned short f2bf(float f) {
  unsigned u = __float_as_uint(f);
  u += 0x7FFFu + ((u >> 16) & 1u);   // round-to-nearest-even
  return (unsigned short)(u >> 16);
}

__device__ __forceinline__ void gld16(const void* gptr, void* ldsptr) {
  __builtin_amdgcn_global_load_lds(
      (__attribute__((address_space(1))) void*)(void*)gptr,
      (__attribute__((address_space(3))) void*)ldsptr, 16, 0, 0);
}

// ---------------- conversions ----------------

__global__ void convert_x_kernel(const float* __restrict__ x,
                                 unsigned short* __restrict__ xb, int n4) {
  int i = blockIdx.x * 256 + threadIdx.x;
  if (i >= n4) return;
  float4 a = ((const float4*)x)[i];
  ushort4 o;
  o.x = f2bf(a.x); o.y = f2bf(a.y); o.z = f2bf(a.z); o.w = f2bf(a.w);
  ((ushort4*)xb)[i] = o;
}

// in: [E][R][Cc] fp32 -> out: [E][Cc][R] bf16 (transposed convert)
__global__ void transpose_conv_kernel(const float* __restrict__ in,
                                      unsigned short* __restrict__ out,
                                      int R, int Cc) {
  __shared__ float tile[32][33];
  int e = blockIdx.z;
  int r0 = blockIdx.y * 32, c0 = blockIdx.x * 32;
  const float* pin = in + (size_t)e * R * Cc;
  unsigned short* pout = out + (size_t)e * R * Cc;
  int tx = threadIdx.x, ty = threadIdx.y;  // 32 x 8
  #pragma unroll
  for (int i = 0; i < 32; i += 8)
    tile[ty + i][tx] = pin[(size_t)(r0 + ty + i) * Cc + c0 + tx];
  __syncthreads();
  #pragma unroll
  for (int i = 0; i < 32; i += 8)
    pout[(size_t)(c0 + ty + i) * R + r0 + tx] = f2bf(tile[tx][ty + i]);
}

// ---------------- gating ----------------
// block = 256 thr = 16 groups of 16 lanes; group handles one token, lane = expert
__global__ __launch_bounds__(256) void gate_kernel(
    const float* __restrict__ x, const float* __restrict__ wg,
    float* __restrict__ w_et, float* __restrict__ phi_sum) {
  __shared__ float wgl[D_DIM * E_EXP];
  __shared__ float phil[E_EXP];
  int tid = threadIdx.x;
  for (int i = tid; i < D_DIM * E_EXP; i += 256) wgl[i] = wg[i];
  if (tid < E_EXP) phil[tid] = 0.f;
  __syncthreads();

  int g = tid >> 4;
  int e = tid & 15;
  int t = blockIdx.x * 16 + g;

  float acc = 0.f;
  const float* xr = x + (size_t)t * D_DIM;
  #pragma unroll 4
  for (int d = 0; d < D_DIM; d += 4) {
    float4 xv = *(const float4*)(xr + d);
    acc = fmaf(xv.x, wgl[(d + 0) * 16 + e], acc);
    acc = fmaf(xv.y, wgl[(d + 1) * 16 + e], acc);
    acc = fmaf(xv.z, wgl[(d + 2) * 16 + e], acc);
    acc = fmaf(xv.w, wgl[(d + 3) * 16 + e], acc);
  }
  // softmax over the 16-lane group
  float m = acc;
  for (int off = 8; off; off >>= 1) m = fmaxf(m, __shfl_xor(m, off));
  float p = expf(acc - m);
  float s = p;
  for (int off = 8; off; off >>= 1) s += __shfl_xor(s, off);
  float score = p / s;
  atomicAdd(&phil[e], score);

  // top-2, lower-index tie-break (matches lax.top_k)
  float v1 = score; int i1 = e;
  for (int off = 8; off; off >>= 1) {
    float ov = __shfl_xor(v1, off); int oi = __shfl_xor(i1, off);
    if (ov > v1 || (ov == v1 && oi < i1)) { v1 = ov; i1 = oi; }
  }
  float sc2 = (e == i1) ? -1.f : score;
  float v2 = sc2; int i2 = e;
  for (int off = 8; off; off >>= 1) {
    float ov = __shfl_xor(v2, off); int oi = __shfl_xor(i2, off);
    if (ov > v2 || (ov == v2 && oi < i2)) { v2 = ov; i2 = oi; }
  }
  if (e == 0) {
    w_et[(size_t)i1 * T_TOK + t] = v1;
    w_et[(size_t)i2 * T_TOK + t] = v2;
  }
  __syncthreads();
  if (tid < E_EXP) atomicAdd(&phi_sum[tid], phil[tid]);
}

__global__ void aux_kernel(const float* __restrict__ phi_sum, float* __restrict__ out_aux) {
  if (threadIdx.x == 0) {
    float s = 0.f;
    for (int e = 0; e < E_EXP; ++e) {
      float pm = phi_sum[e] / (float)T_TOK;
      s += pm * pm;
    }
    *out_aux = (float)E_EXP * s;
  }
}

// ---------------- per-expert top-C selection (exact, tie = lower index) ----------------
__global__ __launch_bounds__(1024) void select_kernel(
    const float* __restrict__ w_et, int* __restrict__ sel_idx, float* __restrict__ sel_w) {
  int e = blockIdx.x, tid = threadIdx.x;
  const float* w = w_et + (size_t)e * T_TOK;
  __shared__ unsigned hist[256];
  __shared__ unsigned scan_buf[1024];
  __shared__ unsigned sh_prefix, sh_k, sh_ngt, sh_cnt;

  unsigned prefix = 0, k = C_CAP, n_gt = 0;
  for (int pass = 0; pass < 4; ++pass) {
    int shift = 24 - pass * 8;
    if (tid < 256) hist[tid] = 0;
    if (tid == 0) sh_cnt = 0;
    __syncthreads();
    for (int i = tid; i < T_TOK; i += 1024) {
      unsigned b = __float_as_uint(w[i]);
      bool match = (pass == 0) || ((b >> (shift + 8)) == (prefix >> (shift + 8)));
      if (match) atomicAdd(&hist[(b >> shift) & 0xFFu], 1u);
    }
    __syncthreads();
    if (tid == 0) {
      unsigned cum = 0; int b = 255;
      for (; b > 0; --b) {
        unsigned c = hist[b];
        if (cum + c >= k) break;
        cum += c;
      }
      sh_prefix = prefix | ((unsigned)b << shift);
      sh_k = k - cum;
      sh_ngt = n_gt + cum;
    }
    __syncthreads();
    prefix = sh_prefix; k = sh_k; n_gt = sh_ngt;
    __syncthreads();
  }

  unsigned thr = prefix;
  unsigned eq_take = k;  // C - n_gt
  int base = tid * 32;

  unsigned myeq = 0;
  for (int i = base; i < base + 32; ++i) {
    float v = w[i];
    unsigned b = __float_as_uint(v);
    if (b > thr) {
      unsigned pos = atomicAdd(&sh_cnt, 1u);
      sel_idx[(size_t)e * C_CAP + pos] = i;
      sel_w[(size_t)e * C_CAP + pos] = v;
    } else if (b == thr) {
      myeq++;
    }
  }
  scan_buf[tid] = myeq;
  __syncthreads();
  for (int off = 1; off < 1024; off <<= 1) {
    unsigned add = (tid >= off) ? scan_buf[tid - off] : 0u;
    __syncthreads();
    scan_buf[tid] += add;
    __syncthreads();
  }
  unsigned excl = scan_buf[tid] - myeq;

  if (thr != 0u) {
    unsigned r = excl;
    for (int i = base; i < base + 32 && r < eq_take; ++i) {
      unsigned b = __float_as_uint(w[i]);
      if (b == thr) {
        sel_idx[(size_t)e * C_CAP + n_gt + r] = i;
        sel_w[(size_t)e * C_CAP + n_gt + r] = w[i];
        r++;
      }
    }
  }
  unsigned m_e = (thr != 0u) ? (unsigned)C_CAP : n_gt;
  for (unsigned i = m_e + tid; i < C_CAP; i += 1024) {
    sel_idx[(size_t)e * C_CAP + i] = 0;
    sel_w[(size_t)e * C_CAP + i] = 0.f;
  }
}

// ---------------- GEMM1: h = gather(x) @ w1[e], SwiGLU fused -> act bf16 ----------------
// grid: e(16) x mt(16) x nt(16); tile 128 tokens x (64 h1-cols + 64 h2-cols); BK=64
__global__ __launch_bounds__(256) void gemm1_kernel(
    const unsigned short* __restrict__ xb,    // [T][D] bf16
    const unsigned short* __restrict__ w1t,   // [E][2F][D] bf16
    const int* __restrict__ sel_idx,          // [E][C]
    unsigned short* __restrict__ act) {       // [E][C][F] bf16
  __shared__ __align__(16) unsigned short As[128 * 64];
  __shared__ __align__(16) unsigned short Bs[128 * 64];
  int bid = blockIdx.x;
  int nt = bid & 15, mt = (bid >> 4) & 15, e = bid >> 8;
  int tid = threadIdx.x, lane = tid & 63, wid = tid >> 6;

  const unsigned short* ag[4];
  const unsigned short* bg[4];
  unsigned lofs[4];
  #pragma unroll
  for (int s = 0; s < 4; ++s) {
    int c = s * 256 + tid;
    int row = c >> 3, kc = c & 7;
    int tok = sel_idx[e * C_CAP + mt * 128 + row];
    ag[s] = xb + (size_t)tok * D_DIM + kc * 8;
    int hcol = (row < 64) ? (nt * 64 + row) : (F_DIM + nt * 64 + (row - 64));
    bg[s] = w1t + ((size_t)e * 2 * F_DIM + hcol) * D_DIM + kc * 8;
    lofs[s] = (unsigned)(s * 256 + wid * 64) * 16;
  }

  f32x4 zero = {0.f, 0.f, 0.f, 0.f};
  f32x4 acc[2][8];
  #pragma unroll
  for (int m = 0; m < 2; ++m)
    #pragma unroll
    for (int n = 0; n < 8; ++n) acc[m][n] = zero;

  int cl = lane & 15, rg = lane >> 4;
  int kof = rg * 8;

  for (int kt = 0; kt < D_DIM / 64; ++kt) {
    #pragma unroll
    for (int s = 0; s < 4; ++s) {
      gld16(ag[s] + kt * 64, (char*)As + lofs[s]);
      gld16(bg[s] + kt * 64, (char*)Bs + lofs[s]);
    }
    __syncthreads();
    #pragma unroll
    for (int kk = 0; kk < 64; kk += 32) {
      bf16x8 a[2], b[8];
      #pragma unroll
      for (int m = 0; m < 2; ++m)
        a[m] = *(const bf16x8*)&As[(wid * 32 + m * 16 + cl) * 64 + kk + kof];
      #pragma unroll
      for (int n = 0; n < 8; ++n)
        b[n] = *(const bf16x8*)&Bs[(n * 16 + cl) * 64 + kk + kof];
      #pragma unroll
      for (int m = 0; m < 2; ++m)
        #pragma unroll
        for (int n = 0; n < 8; ++n)
          acc[m][n] = __builtin_amdgcn_mfma_f32_16x16x32_bf16(a[m], b[n], acc[m][n], 0, 0, 0);
    }
    __syncthreads();
  }

  // SwiGLU epilogue: act col j = h1[j] * silu(h2[j]); frag n pairs with frag n+4
  #pragma unroll
  for (int m = 0; m < 2; ++m) {
    #pragma unroll
    for (int n = 0; n < 4; ++n) {
      #pragma unroll
      for (int r = 0; r < 4; ++r) {
        int row = mt * 128 + wid * 32 + m * 16 + rg * 4 + r;
        int col = nt * 64 + n * 16 + cl;
        float h1 = acc[m][n][r];
        float h2 = acc[m][n + 4][r];
        float sg = h2 / (1.f + expf(-h2));
        act[((size_t)e * C_CAP + row) * F_DIM + col] = f2bf(h1 * sg);
      }
    }
  }
}

// ---------------- GEMM2: out = act @ w2[e] * sel_w, scatter-add ----------------
// grid: e(16) x mt(16) x nt(4); tile 128 x 128; BK=64
__global__ __launch_bounds__(256) void gemm2_kernel(
    const unsigned short* __restrict__ act,   // [E][C][F] bf16
    const unsigned short* __restrict__ w2t,   // [E][D][F] bf16
    const int* __restrict__ sel_idx,
    const float* __restrict__ sel_w,
    float* __restrict__ out) {                // [T][D] fp32
  __shared__ __align__(16) unsigned short As[128 * 64];
  __shared__ __align__(16) unsigned short Bs[128 * 64];
  int bid = blockIdx.x;
  int nt = bid & 3, mt = (bid >> 2) & 15, e = bid >> 6;
  int tid = threadIdx.x, lane = tid & 63, wid = tid >> 6;
  int wr = wid >> 1, wc = wid & 1;

  const unsigned short* ag[4];
  const unsigned short* bg[4];
  unsigned lofs[4];
  #pragma unroll
  for (int s = 0; s < 4; ++s) {
    int c = s * 256 + tid;
    int row = c >> 3, kc = c & 7;
    ag[s] = act + ((size_t)e * C_CAP + mt * 128 + row) * F_DIM + kc * 8;
    int dcol = nt * 128 + row;
    bg[s] = w2t + ((size_t)e * D_DIM + dcol) * F_DIM + kc * 8;
    lofs[s] = (unsigned)(s * 256 + wid * 64) * 16;
  }

  f32x4 zero = {0.f, 0.f, 0.f, 0.f};
  f32x4 acc[4][4];
  #pragma unroll
  for (int m = 0; m < 4; ++m)
    #pragma unroll
    for (int n = 0; n < 4; ++n) acc[m][n] = zero;

  int cl = lane & 15, rg = lane >> 4;
  int kof = rg * 8;

  for (int kt = 0; kt < F_DIM / 64; ++kt) {
    #pragma unroll
    for (int s = 0; s < 4; ++s) {
      gld16(ag[s] + kt * 64, (char*)As + lofs[s]);
      gld16(bg[s] + kt * 64, (char*)Bs + lofs[s]);
    }
    __syncthreads();
    #pragma unroll
    for (int kk = 0; kk < 64; kk += 32) {
      bf16x8 a[4], b[4];
      #pragma unroll
      for (int m = 0; m < 4; ++m)
        a[m] = *(const bf16x8*)&As[(wr * 64 + m * 16 + cl) * 64 + kk + kof];
      #pragma unroll
      for (int n = 0; n < 4; ++n)
        b[n] = *(const bf16x8*)&Bs[(wc * 64 + n * 16 + cl) * 64 + kk + kof];
      #pragma unroll
      for (int m = 0; m < 4; ++m)
        #pragma unroll
        for (int n = 0; n < 4; ++n)
          acc[m][n] = __builtin_amdgcn_mfma_f32_16x16x32_bf16(a[m], b[n], acc[m][n], 0, 0, 0);
    }
    __syncthreads();
  }

  #pragma unroll
  for (int m = 0; m < 4; ++m) {
    #pragma unroll
    for (int r = 0; r < 4; ++r) {
      int slot = mt * 128 + wr * 64 + m * 16 + rg * 4 + r;
      float wgt = sel_w[e * C_CAP + slot];
      int tok = sel_idx[e * C_CAP + slot];
      float* orow = out + (size_t)tok * D_DIM;
      #pragma unroll
      for (int n = 0; n < 4; ++n) {
        int col = nt * 128 + wc * 64 + n * 16 + cl;
        atomicAdd(&orow[col], acc[m][n][r] * wgt);
      }
    }
  }
}

// ---------------- launch ----------------
extern "C" void kernel_launch(void* const* d_in, const int* in_sizes, int n_in,
                              void* d_out, int out_size, void* d_ws, size_t ws_size,
                              hipStream_t stream) {
  const float* x  = (const float*)d_in[0];
  const float* wg = (const float*)d_in[1];
  const float* w1 = (const float*)d_in[2];
  const float* w2 = (const float*)d_in[3];
  float* out = (float*)d_out;

  char* ws = (char*)d_ws;
  size_t off = 0;
  auto carve = [&](size_t bytes) -> void* {
    void* p = ws + off;
    off += (bytes + 255) & ~(size_t)255;
    return p;
  };
  float* w_et            = (float*)carve((size_t)E_EXP * T_TOK * 4);
  float* phi             = (float*)carve(64);
  int* sel_i             = (int*)carve((size_t)E_EXP * C_CAP * 4);
  float* sel_wv          = (float*)carve((size_t)E_EXP * C_CAP * 4);
  unsigned short* xb     = (unsigned short*)carve((size_t)T_TOK * D_DIM * 2);
  unsigned short* w1t    = (unsigned short*)carve((size_t)E_EXP * 2 * F_DIM * D_DIM * 2);
  unsigned short* w2t    = (unsigned short*)carve((size_t)E_EXP * D_DIM * F_DIM * 2);
  unsigned short* actb   = (unsigned short*)carve((size_t)E_EXP * C_CAP * F_DIM * 2);
  if (off > ws_size) return;  // workspace too small -> fail loudly (validation will catch)

  hipMemsetAsync(w_et, 0, (size_t)E_EXP * T_TOK * 4, stream);
  hipMemsetAsync(phi, 0, 64, stream);
  hipMemsetAsync(d_out, 0, (size_t)out_size * 4, stream);

  convert_x_kernel<<<(T_TOK * D_DIM / 4 + 255) / 256, 256, 0, stream>>>(
      x, xb, T_TOK * D_DIM / 4);
  transpose_conv_kernel<<<dim3(2 * F_DIM / 32, D_DIM / 32, E_EXP), dim3(32, 8), 0, stream>>>(
      w1, w1t, D_DIM, 2 * F_DIM);
  transpose_conv_kernel<<<dim3(D_DIM / 32, F_DIM / 32, E_EXP), dim3(32, 8), 0, stream>>>(
      w2, w2t, F_DIM, D_DIM);
  gate_kernel<<<T_TOK / 16, 256, 0, stream>>>(x, wg, w_et, phi);
  select_kernel<<<E_EXP, 1024, 0, stream>>>(w_et, sel_i, sel_wv);
  aux_kernel<<<1, 64, 0, stream>>>(phi, out + (size_t)T_TOK * D_DIM);
  gemm1_kernel<<<E_EXP * 16 * 16, 256, 0, stream>>>(xb, w1t, sel_i, actb);
  gemm2_kernel<<<E_EXP * 16 * 4, 256, 0, stream>>>(actb, w2t, sel_i, sel_wv, out);
}

// Round 2
// 410.607 us; speedup vs baseline: 1.1426x; 1.1426x over previous
//
#include <hip/hip_runtime.h>
#include <hip/hip_bf16.h>
#include <math.h>

#define T_TOK 32768
#define D_DIM 512
#define E_EXP 16
#define F_DIM 1024
#define C_CAP 2048

typedef __attribute__((ext_vector_type(8))) __bf16 bf16x8;
typedef __attribute__((ext_vector_type(4))) float f32x4;

__device__ __forceinline__ unsigned short f2bf(float f) {
  unsigned u = __float_as_uint(f);
  u += 0x7FFFu + ((u >> 16) & 1u);   // round-to-nearest-even
  return (unsigned short)(u >> 16);
}

__device__ __forceinline__ void gld16(const void* gptr, void* ldsptr) {
  __builtin_amdgcn_global_load_lds(
      (__attribute__((address_space(1))) void*)(void*)gptr,
      (__attribute__((address_space(3))) void*)ldsptr, 16, 0, 0);
}

// in: [E][R][Cc] fp32 -> out: [E][Cc][R] bf16 (transposed convert)
__global__ void transpose_conv_kernel(const float* __restrict__ in,
                                      unsigned short* __restrict__ out,
                                      int R, int Cc) {
  __shared__ float tile[32][33];
  int e = blockIdx.z;
  int r0 = blockIdx.y * 32, c0 = blockIdx.x * 32;
  const float* pin = in + (size_t)e * R * Cc;
  unsigned short* pout = out + (size_t)e * R * Cc;
  int tx = threadIdx.x, ty = threadIdx.y;  // 32 x 8
  #pragma unroll
  for (int i = 0; i < 32; i += 8)
    tile[ty + i][tx] = pin[(size_t)(r0 + ty + i) * Cc + c0 + tx];
  __syncthreads();
  #pragma unroll
  for (int i = 0; i < 32; i += 8)
    pout[(size_t)(c0 + ty + i) * R + r0 + tx] = f2bf(tile[tx][ty + i]);
}

// ---------------- gating (+ fused x -> bf16 conversion) ----------------
// block = 256 thr = 16 groups of 16 lanes; group handles one token, lane = expert
__global__ __launch_bounds__(256) void gate_kernel(
    const float* __restrict__ x, const float* __restrict__ wg,
    float* __restrict__ w_et, float* __restrict__ phi_sum,
    unsigned short* __restrict__ xb) {
  __shared__ float wgl[D_DIM * E_EXP];
  __shared__ float phil[E_EXP];
  int tid = threadIdx.x;
  for (int i = tid; i < D_DIM * E_EXP; i += 256) wgl[i] = wg[i];
  if (tid < E_EXP) phil[tid] = 0.f;
  __syncthreads();

  int g = tid >> 4;
  int e = tid & 15;
  int t = blockIdx.x * 16 + g;

  float acc = 0.f;
  const float* xr = x + (size_t)t * D_DIM;
  #pragma unroll 4
  for (int d = 0; d < D_DIM; d += 4) {
    float4 xv = *(const float4*)(xr + d);
    acc = fmaf(xv.x, wgl[(d + 0) * 16 + e], acc);
    acc = fmaf(xv.y, wgl[(d + 1) * 16 + e], acc);
    acc = fmaf(xv.z, wgl[(d + 2) * 16 + e], acc);
    acc = fmaf(xv.w, wgl[(d + 3) * 16 + e], acc);
  }

  // fused conversion: group lanes cover the row coalesced (16 float4 = 256B/iter)
  unsigned short* xrow = xb + (size_t)t * D_DIM;
  #pragma unroll
  for (int j = 0; j < 8; ++j) {
    int idx = j * 16 + e;  // float4 index within row
    float4 v = *(const float4*)(xr + idx * 4);
    ushort4 o;
    o.x = f2bf(v.x); o.y = f2bf(v.y); o.z = f2bf(v.z); o.w = f2bf(v.w);
    ((ushort4*)xrow)[idx] = o;
  }

  // softmax over the 16-lane group
  float m = acc;
  for (int off = 8; off; off >>= 1) m = fmaxf(m, __shfl_xor(m, off));
  float p = expf(acc - m);
  float s = p;
  for (int off = 8; off; off >>= 1) s += __shfl_xor(s, off);
  float score = p / s;
  atomicAdd(&phil[e], score);

  // top-2, lower-index tie-break (matches lax.top_k)
  float v1 = score; int i1 = e;
  for (int off = 8; off; off >>= 1) {
    float ov = __shfl_xor(v1, off); int oi = __shfl_xor(i1, off);
    if (ov > v1 || (ov == v1 && oi < i1)) { v1 = ov; i1 = oi; }
  }
  float sc2 = (e == i1) ? -1.f : score;
  float v2 = sc2; int i2 = e;
  for (int off = 8; off; off >>= 1) {
    float ov = __shfl_xor(v2, off); int oi = __shfl_xor(i2, off);
    if (ov > v2 || (ov == v2 && oi < i2)) { v2 = ov; i2 = oi; }
  }
  if (e == 0) {
    w_et[(size_t)i1 * T_TOK + t] = v1;
    w_et[(size_t)i2 * T_TOK + t] = v2;
  }
  __syncthreads();
  if (tid < E_EXP) atomicAdd(&phi_sum[tid], phil[tid]);
}

__global__ void aux_kernel(const float* __restrict__ phi_sum, float* __restrict__ out_aux) {
  if (threadIdx.x == 0) {
    float s = 0.f;
    for (int e = 0; e < E_EXP; ++e) {
      float pm = phi_sum[e] / (float)T_TOK;
      s += pm * pm;
    }
    *out_aux = (float)E_EXP * s;
  }
}

// ---------------- per-expert top-C selection (exact, tie = lower index) ----------------
__global__ __launch_bounds__(1024) void select_kernel(
    const float* __restrict__ w_et, int* __restrict__ sel_idx, float* __restrict__ sel_w) {
  int e = blockIdx.x, tid = threadIdx.x;
  const float* w = w_et + (size_t)e * T_TOK;
  __shared__ unsigned hist[256];
  __shared__ unsigned scan_buf[1024];
  __shared__ unsigned sh_prefix, sh_k, sh_ngt, sh_cnt;

  unsigned prefix = 0, k = C_CAP, n_gt = 0;
  for (int pass = 0; pass < 4; ++pass) {
    int shift = 24 - pass * 8;
    if (tid < 256) hist[tid] = 0;
    if (tid == 0) sh_cnt = 0;
    __syncthreads();
    for (int i = tid; i < T_TOK; i += 1024) {
      unsigned b = __float_as_uint(w[i]);
      bool match = (pass == 0) || ((b >> (shift + 8)) == (prefix >> (shift + 8)));
      if (match) atomicAdd(&hist[(b >> shift) & 0xFFu], 1u);
    }
    __syncthreads();
    if (tid == 0) {
      unsigned cum = 0; int b = 255;
      for (; b > 0; --b) {
        unsigned c = hist[b];
        if (cum + c >= k) break;
        cum += c;
      }
      sh_prefix = prefix | ((unsigned)b << shift);
      sh_k = k - cum;
      sh_ngt = n_gt + cum;
    }
    __syncthreads();
    prefix = sh_prefix; k = sh_k; n_gt = sh_ngt;
    __syncthreads();
  }

  unsigned thr = prefix;
  unsigned eq_take = k;  // C - n_gt
  int base = tid * 32;

  unsigned myeq = 0;
  for (int i = base; i < base + 32; ++i) {
    float v = w[i];
    unsigned b = __float_as_uint(v);
    if (b > thr) {
      unsigned pos = atomicAdd(&sh_cnt, 1u);
      sel_idx[(size_t)e * C_CAP + pos] = i;
      sel_w[(size_t)e * C_CAP + pos] = v;
    } else if (b == thr) {
      myeq++;
    }
  }
  scan_buf[tid] = myeq;
  __syncthreads();
  for (int off = 1; off < 1024; off <<= 1) {
    unsigned add = (tid >= off) ? scan_buf[tid - off] : 0u;
    __syncthreads();
    scan_buf[tid] += add;
    __syncthreads();
  }
  unsigned excl = scan_buf[tid] - myeq;

  if (thr != 0u) {
    unsigned r = excl;
    for (int i = base; i < base + 32 && r < eq_take; ++i) {
      unsigned b = __float_as_uint(w[i]);
      if (b == thr) {
        sel_idx[(size_t)e * C_CAP + n_gt + r] = i;
        sel_w[(size_t)e * C_CAP + n_gt + r] = w[i];
        r++;
      }
    }
  }
  unsigned m_e = (thr != 0u) ? (unsigned)C_CAP : n_gt;
  for (unsigned i = m_e + tid; i < C_CAP; i += 1024) {
    sel_idx[(size_t)e * C_CAP + i] = 0;
    sel_w[(size_t)e * C_CAP + i] = 0.f;
  }
}

// ---------------- GEMM1: h = gather(x) @ w1[e], SwiGLU fused -> act bf16 ----------------
// grid: e(16) x mt(16) x nt(16); tile 128 tokens x (64 h1-cols + 64 h2-cols); BK=64
// LDS tiles XOR-swizzled: linear dest + pre-swizzled global src + swizzled read (rule #21)
__global__ __launch_bounds__(256) void gemm1_kernel(
    const unsigned short* __restrict__ xb,    // [T][D] bf16
    const unsigned short* __restrict__ w1t,   // [E][2F][D] bf16
    const int* __restrict__ sel_idx,          // [E][C]
    unsigned short* __restrict__ act) {       // [E][C][F] bf16
  __shared__ __align__(16) unsigned short As[128 * 64];
  __shared__ __align__(16) unsigned short Bs[128 * 64];
  // XCD-bijective swizzle (grid 4096 = 8*512)
  int bid = (blockIdx.x & 7) * 512 + (blockIdx.x >> 3);
  int nt = bid & 15, mt = (bid >> 4) & 15, e = bid >> 8;
  int tid = threadIdx.x, lane = tid & 63, wid = tid >> 6;

  const unsigned short* ag[4];
  const unsigned short* bg[4];
  unsigned lofs[4];
  #pragma unroll
  for (int s = 0; s < 4; ++s) {
    int c = s * 256 + tid;
    int row = c >> 3, kc = c & 7;
    int kcs = kc ^ (row & 7);          // pre-swizzled source chunk
    int tok = sel_idx[e * C_CAP + mt * 128 + row];
    ag[s] = xb + (size_t)tok * D_DIM + kcs * 8;
    int hcol = (row < 64) ? (nt * 64 + row) : (F_DIM + nt * 64 + (row - 64));
    bg[s] = w1t + ((size_t)e * 2 * F_DIM + hcol) * D_DIM + kcs * 8;
    lofs[s] = (unsigned)(s * 256 + wid * 64) * 16;
  }

  f32x4 zero = {0.f, 0.f, 0.f, 0.f};
  f32x4 acc[2][8];
  #pragma unroll
  for (int m = 0; m < 2; ++m)
    #pragma unroll
    for (int n = 0; n < 8; ++n) acc[m][n] = zero;

  int cl = lane & 15, rg = lane >> 4;
  int sw = cl & 7;

  for (int kt = 0; kt < D_DIM / 64; ++kt) {
    #pragma unroll
    for (int s = 0; s < 4; ++s) {
      gld16(ag[s] + kt * 64, (char*)As + lofs[s]);
      gld16(bg[s] + kt * 64, (char*)Bs + lofs[s]);
    }
    __syncthreads();
    #pragma unroll
    for (int kk = 0; kk < 64; kk += 32) {
      int cofs = (((kk >> 3) + rg) ^ sw) << 3;  // swizzled 16B-chunk offset
      bf16x8 a[2], b[8];
      #pragma unroll
      for (int m = 0; m < 2; ++m)
        a[m] = *(const bf16x8*)&As[(wid * 32 + m * 16 + cl) * 64 + cofs];
      #pragma unroll
      for (int n = 0; n < 8; ++n)
        b[n] = *(const bf16x8*)&Bs[(n * 16 + cl) * 64 + cofs];
      #pragma unroll
      for (int m = 0; m < 2; ++m)
        #pragma unroll
        for (int n = 0; n < 8; ++n)
          acc[m][n] = __builtin_amdgcn_mfma_f32_16x16x32_bf16(a[m], b[n], acc[m][n], 0, 0, 0);
    }
    __syncthreads();
  }

  // SwiGLU epilogue: act col j = h1[j] * silu(h2[j]); frag n pairs with frag n+4
  #pragma unroll
  for (int m = 0; m < 2; ++m) {
    #pragma unroll
    for (int n = 0; n < 4; ++n) {
      #pragma unroll
      for (int r = 0; r < 4; ++r) {
        int row = mt * 128 + wid * 32 + m * 16 + rg * 4 + r;
        int col = nt * 64 + n * 16 + cl;
        float h1 = acc[m][n][r];
        float h2 = acc[m][n + 4][r];
        float sg = h2 / (1.f + __expf(-h2));
        act[((size_t)e * C_CAP + row) * F_DIM + col] = f2bf(h1 * sg);
      }
    }
  }
}

// ---------------- GEMM2: out = act @ w2[e] * sel_w, scatter-add ----------------
// grid: e(16) x mt(16) x nt(4); tile 128 x 128; BK=64
__global__ __launch_bounds__(256) void gemm2_kernel(
    const unsigned short* __restrict__ act,   // [E][C][F] bf16
    const unsigned short* __restrict__ w2t,   // [E][D][F] bf16
    const int* __restrict__ sel_idx,
    const float* __restrict__ sel_w,
    float* __restrict__ out) {                // [T][D] fp32
  __shared__ __align__(16) unsigned short As[128 * 64];
  __shared__ __align__(16) unsigned short Bs[128 * 64];
  // XCD-bijective swizzle (grid 1024 = 8*128)
  int bid = (blockIdx.x & 7) * 128 + (blockIdx.x >> 3);
  int nt = bid & 3, mt = (bid >> 2) & 15, e = bid >> 6;
  int tid = threadIdx.x, lane = tid & 63, wid = tid >> 6;
  int wr = wid >> 1, wc = wid & 1;

  const unsigned short* ag[4];
  const unsigned short* bg[4];
  unsigned lofs[4];
  #pragma unroll
  for (int s = 0; s < 4; ++s) {
    int c = s * 256 + tid;
    int row = c >> 3, kc = c & 7;
    int kcs = kc ^ (row & 7);
    ag[s] = act + ((size_t)e * C_CAP + mt * 128 + row) * F_DIM + kcs * 8;
    int dcol = nt * 128 + row;
    bg[s] = w2t + ((size_t)e * D_DIM + dcol) * F_DIM + kcs * 8;
    lofs[s] = (unsigned)(s * 256 + wid * 64) * 16;
  }

  f32x4 zero = {0.f, 0.f, 0.f, 0.f};
  f32x4 acc[4][4];
  #pragma unroll
  for (int m = 0; m < 4; ++m)
    #pragma unroll
    for (int n = 0; n < 4; ++n) acc[m][n] = zero;

  int cl = lane & 15, rg = lane >> 4;
  int sw = cl & 7;

  for (int kt = 0; kt < F_DIM / 64; ++kt) {
    #pragma unroll
    for (int s = 0; s < 4; ++s) {
      gld16(ag[s] + kt * 64, (char*)As + lofs[s]);
      gld16(bg[s] + kt * 64, (char*)Bs + lofs[s]);
    }
    __syncthreads();
    #pragma unroll
    for (int kk = 0; kk < 64; kk += 32) {
      int cofs = (((kk >> 3) + rg) ^ sw) << 3;
      bf16x8 a[4], b[4];
      #pragma unroll
      for (int m = 0; m < 4; ++m)
        a[m] = *(const bf16x8*)&As[(wr * 64 + m * 16 + cl) * 64 + cofs];
      #pragma unroll
      for (int n = 0; n < 4; ++n)
        b[n] = *(const bf16x8*)&Bs[(wc * 64 + n * 16 + cl) * 64 + cofs];
      #pragma unroll
      for (int m = 0; m < 4; ++m)
        #pragma unroll
        for (int n = 0; n < 4; ++n)
          acc[m][n] = __builtin_amdgcn_mfma_f32_16x16x32_bf16(a[m], b[n], acc[m][n], 0, 0, 0);
    }
    __syncthreads();
  }

  #pragma unroll
  for (int m = 0; m < 4; ++m) {
    #pragma unroll
    for (int r = 0; r < 4; ++r) {
      int slot = mt * 128 + wr * 64 + m * 16 + rg * 4 + r;
      float wgt = sel_w[e * C_CAP + slot];
      int tok = sel_idx[e * C_CAP + slot];
      float* orow = out + (size_t)tok * D_DIM;
      #pragma unroll
      for (int n = 0; n < 4; ++n) {
        int col = nt * 128 + wc * 64 + n * 16 + cl;
        atomicAdd(&orow[col], acc[m][n][r] * wgt);
      }
    }
  }
}

// ---------------- launch ----------------
extern "C" void kernel_launch(void* const* d_in, const int* in_sizes, int n_in,
                              void* d_out, int out_size, void* d_ws, size_t ws_size,
                              hipStream_t stream) {
  const float* x  = (const float*)d_in[0];
  const float* wg = (const float*)d_in[1];
  const float* w1 = (const float*)d_in[2];
  const float* w2 = (const float*)d_in[3];
  float* out = (float*)d_out;

  char* ws = (char*)d_ws;
  size_t off = 0;
  auto carve = [&](size_t bytes) -> void* {
    void* p = ws + off;
    off += (bytes + 255) & ~(size_t)255;
    return p;
  };
  float* w_et            = (float*)carve((size_t)E_EXP * T_TOK * 4);
  float* phi             = (float*)carve(64);
  int* sel_i             = (int*)carve((size_t)E_EXP * C_CAP * 4);
  float* sel_wv          = (float*)carve((size_t)E_EXP * C_CAP * 4);
  unsigned short* xb     = (unsigned short*)carve((size_t)T_TOK * D_DIM * 2);
  unsigned short* w1t    = (unsigned short*)carve((size_t)E_EXP * 2 * F_DIM * D_DIM * 2);
  unsigned short* w2t    = (unsigned short*)carve((size_t)E_EXP * D_DIM * F_DIM * 2);
  unsigned short* actb   = (unsigned short*)carve((size_t)E_EXP * C_CAP * F_DIM * 2);
  if (off > ws_size) return;

  hipMemsetAsync(w_et, 0, (size_t)E_EXP * T_TOK * 4, stream);
  hipMemsetAsync(phi, 0, 64, stream);
  hipMemsetAsync(d_out, 0, (size_t)out_size * 4, stream);

  transpose_conv_kernel<<<dim3(2 * F_DIM / 32, D_DIM / 32, E_EXP), dim3(32, 8), 0, stream>>>(
      w1, w1t, D_DIM, 2 * F_DIM);
  transpose_conv_kernel<<<dim3(D_DIM / 32, F_DIM / 32, E_EXP), dim3(32, 8), 0, stream>>>(
      w2, w2t, F_DIM, D_DIM);
  gate_kernel<<<T_TOK / 16, 256, 0, stream>>>(x, wg, w_et, phi, xb);
  select_kernel<<<E_EXP, 1024, 0, stream>>>(w_et, sel_i, sel_wv);
  aux_kernel<<<1, 64, 0, stream>>>(phi, out + (size_t)T_TOK * D_DIM);
  gemm1_kernel<<<E_EXP * 16 * 16, 256, 0, stream>>>(xb, w1t, sel_i, actb);
  gemm2_kernel<<<E_EXP * 16 * 4, 256, 0, stream>>>(actb, w2t, sel_i, sel_wv, out);
}

// Round 3
// 399.986 us; speedup vs baseline: 1.1729x; 1.0266x over previous
//
#include <hip/hip_runtime.h>
#include <hip/hip_bf16.h>
#include <math.h>

#define T_TOK 32768
#define D_DIM 512
#define E_EXP 16
#define F_DIM 1024
#define C_CAP 2048

typedef __attribute__((ext_vector_type(8))) __bf16 bf16x8;
typedef __attribute__((ext_vector_type(4))) float f32x4;

__device__ __forceinline__ unsigned short f2bf(float f) {
  unsigned u = __float_as_uint(f);
  u += 0x7FFFu + ((u >> 16) & 1u);   // round-to-nearest-even
  return (unsigned short)(u >> 16);
}

__device__ __forceinline__ void gld16(const void* gptr, void* ldsptr) {
  __builtin_amdgcn_global_load_lds(
      (__attribute__((address_space(1))) void*)(void*)gptr,
      (__attribute__((address_space(3))) void*)ldsptr, 16, 0, 0);
}

// in: [E][R][Cc] fp32 -> out: [E][Cc][R] bf16 (transposed convert)
__global__ void transpose_conv_kernel(const float* __restrict__ in,
                                      unsigned short* __restrict__ out,
                                      int R, int Cc) {
  __shared__ float tile[32][33];
  int e = blockIdx.z;
  int r0 = blockIdx.y * 32, c0 = blockIdx.x * 32;
  const float* pin = in + (size_t)e * R * Cc;
  unsigned short* pout = out + (size_t)e * R * Cc;
  int tx = threadIdx.x, ty = threadIdx.y;  // 32 x 8
  #pragma unroll
  for (int i = 0; i < 32; i += 8)
    tile[ty + i][tx] = pin[(size_t)(r0 + ty + i) * Cc + c0 + tx];
  __syncthreads();
  #pragma unroll
  for (int i = 0; i < 32; i += 8)
    pout[(size_t)(c0 + ty + i) * R + r0 + tx] = f2bf(tile[tx][ty + i]);
}

// ---------------- gating (+ fused x -> bf16 conversion) ----------------
// block = 256 thr = 16 groups of 16 lanes; group handles one token, lane = expert
__global__ __launch_bounds__(256) void gate_kernel(
    const float* __restrict__ x, const float* __restrict__ wg,
    float* __restrict__ w_et, float* __restrict__ phi_sum,
    unsigned short* __restrict__ xb) {
  __shared__ float wgl[D_DIM * E_EXP];
  __shared__ float phil[E_EXP];
  int tid = threadIdx.x;
  for (int i = tid; i < D_DIM * E_EXP; i += 256) wgl[i] = wg[i];
  if (tid < E_EXP) phil[tid] = 0.f;
  __syncthreads();

  int g = tid >> 4;
  int e = tid & 15;
  int t = blockIdx.x * 16 + g;

  float acc = 0.f;
  const float* xr = x + (size_t)t * D_DIM;
  #pragma unroll 4
  for (int d = 0; d < D_DIM; d += 4) {
    float4 xv = *(const float4*)(xr + d);
    acc = fmaf(xv.x, wgl[(d + 0) * 16 + e], acc);
    acc = fmaf(xv.y, wgl[(d + 1) * 16 + e], acc);
    acc = fmaf(xv.z, wgl[(d + 2) * 16 + e], acc);
    acc = fmaf(xv.w, wgl[(d + 3) * 16 + e], acc);
  }

  // fused conversion: group lanes cover the row coalesced (16 float4 = 256B/iter)
  unsigned short* xrow = xb + (size_t)t * D_DIM;
  #pragma unroll
  for (int j = 0; j < 8; ++j) {
    int idx = j * 16 + e;  // float4 index within row
    float4 v = *(const float4*)(xr + idx * 4);
    ushort4 o;
    o.x = f2bf(v.x); o.y = f2bf(v.y); o.z = f2bf(v.z); o.w = f2bf(v.w);
    ((ushort4*)xrow)[idx] = o;
  }

  // softmax over the 16-lane group
  float m = acc;
  for (int off = 8; off; off >>= 1) m = fmaxf(m, __shfl_xor(m, off));
  float p = expf(acc - m);
  float s = p;
  for (int off = 8; off; off >>= 1) s += __shfl_xor(s, off);
  float score = p / s;
  atomicAdd(&phil[e], score);

  // top-2, lower-index tie-break (matches lax.top_k)
  float v1 = score; int i1 = e;
  for (int off = 8; off; off >>= 1) {
    float ov = __shfl_xor(v1, off); int oi = __shfl_xor(i1, off);
    if (ov > v1 || (ov == v1 && oi < i1)) { v1 = ov; i1 = oi; }
  }
  float sc2 = (e == i1) ? -1.f : score;
  float v2 = sc2; int i2 = e;
  for (int off = 8; off; off >>= 1) {
    float ov = __shfl_xor(v2, off); int oi = __shfl_xor(i2, off);
    if (ov > v2 || (ov == v2 && oi < i2)) { v2 = ov; i2 = oi; }
  }
  if (e == 0) {
    w_et[(size_t)i1 * T_TOK + t] = v1;
    w_et[(size_t)i2 * T_TOK + t] = v2;
  }
  __syncthreads();
  if (tid < E_EXP) atomicAdd(&phi_sum[tid], phil[tid]);
}

__global__ void aux_kernel(const float* __restrict__ phi_sum, float* __restrict__ out_aux) {
  if (threadIdx.x == 0) {
    float s = 0.f;
    for (int e = 0; e < E_EXP; ++e) {
      float pm = phi_sum[e] / (float)T_TOK;
      s += pm * pm;
    }
    *out_aux = (float)E_EXP * s;
  }
}

// ---------------- per-expert top-C selection (exact, tie = lower index) ----------------
// Radix select on fp32 bits (all values >= 0). Per-wave privatized histograms to
// kill same-bin atomic contention; packed (gt,eq) wave scan for deterministic
// compaction with no position atomics. Order within the set is irrelevant downstream.
__global__ __launch_bounds__(1024) void select_kernel(
    const float* __restrict__ w_et, int* __restrict__ sel_idx, float* __restrict__ sel_w) {
  int e = blockIdx.x, tid = threadIdx.x;
  int lane = tid & 63, wv = tid >> 6;
  const float* w = w_et + (size_t)e * T_TOK;
  __shared__ unsigned hist[16][256];   // per-wave privatized
  __shared__ unsigned red[256];
  __shared__ unsigned wsum[16];
  __shared__ unsigned sh_prefix, sh_k, sh_ngt;

  unsigned prefix = 0, k = C_CAP, n_gt = 0;
  for (int pass = 0; pass < 4; ++pass) {
    int shift = 24 - pass * 8;
    for (int i = tid; i < 16 * 256; i += 1024) ((unsigned*)hist)[i] = 0;
    __syncthreads();
    for (int i = tid; i < T_TOK; i += 1024) {
      unsigned b = __float_as_uint(w[i]);
      bool match = (pass == 0) || ((b >> (shift + 8)) == (prefix >> (shift + 8)));
      if (match) atomicAdd(&hist[wv][(b >> shift) & 0xFFu], 1u);
    }
    __syncthreads();
    if (tid < 256) {
      unsigned t = 0;
      #pragma unroll
      for (int wq = 0; wq < 16; ++wq) t += hist[wq][tid];
      red[tid] = t;
    }
    __syncthreads();
    if (tid == 0) {
      unsigned cum = 0; int b = 255;
      for (; b > 0; --b) {
        unsigned c = red[b];
        if (cum + c >= k) break;
        cum += c;
      }
      sh_prefix = prefix | ((unsigned)b << shift);
      sh_k = k - cum;
      sh_ngt = n_gt + cum;
    }
    __syncthreads();
    prefix = sh_prefix; k = sh_k; n_gt = sh_ngt;
    __syncthreads();
  }

  unsigned thr = prefix;
  unsigned eq_take = k;  // C - n_gt; >= 1
  int base = tid * 32;

  // count my gt / eq (packed: gt<<16 | eq; each component < 65536)
  unsigned mygt = 0, myeq = 0;
  for (int i = base; i < base + 32; ++i) {
    unsigned b = __float_as_uint(w[i]);
    if (b > thr) mygt++;
    else if (b == thr) myeq++;
  }
  unsigned val = (mygt << 16) | myeq;
  unsigned inc = val;
  #pragma unroll
  for (int off = 1; off < 64; off <<= 1) {
    unsigned o = __shfl_up(inc, off);
    if (lane >= off) inc += o;
  }
  if (lane == 63) wsum[wv] = inc;
  __syncthreads();
  if (tid == 0) {
    unsigned c = 0;
    #pragma unroll
    for (int q = 0; q < 16; ++q) { unsigned t = wsum[q]; wsum[q] = c; c += t; }
  }
  __syncthreads();
  unsigned excl = wsum[wv] + inc - val;
  unsigned rgt = excl >> 16;
  unsigned req = excl & 0xFFFFu;

  int* si = sel_idx + (size_t)e * C_CAP;
  float* swp = sel_w + (size_t)e * C_CAP;
  for (int i = base; i < base + 32; ++i) {
    float v = w[i];
    unsigned b = __float_as_uint(v);
    if (b > thr) {
      si[rgt] = i; swp[rgt] = v; rgt++;
    } else if (b == thr && req < eq_take) {
      si[n_gt + req] = i; swp[n_gt + req] = v; req++;
    }
  }
}

// ---------------- GEMM1: h = gather(x) @ w1[e], SwiGLU fused -> act bf16 ----------------
// grid: e(16) x mt(16) x nt(16); tile 128 tokens x (64 h1 + 64 h2 cols); BK=64
// Double-buffered LDS with prefetch: stage(t+1) issued BEFORE compute(t); one
// barrier per K-step (its implicit vmcnt(0) lands after a full compute phase).
// LDS XOR-swizzle: linear dest + pre-swizzled global src + swizzled read.
__global__ __launch_bounds__(256) void gemm1_kernel(
    const unsigned short* __restrict__ xb,    // [T][D] bf16
    const unsigned short* __restrict__ w1t,   // [E][2F][D] bf16
    const int* __restrict__ sel_idx,          // [E][C]
    unsigned short* __restrict__ act) {       // [E][C][F] bf16
  __shared__ __align__(16) unsigned short As[2][128 * 64];
  __shared__ __align__(16) unsigned short Bs[2][128 * 64];
  // XCD-bijective swizzle (grid 4096 = 8*512)
  int bid = (blockIdx.x & 7) * 512 + (blockIdx.x >> 3);
  int nt = bid & 15, mt = (bid >> 4) & 15, e = bid >> 8;
  int tid = threadIdx.x, lane = tid & 63, wid = tid >> 6;

  const unsigned short* ag[4];
  const unsigned short* bg[4];
  unsigned lofs[4];
  #pragma unroll
  for (int s = 0; s < 4; ++s) {
    int c = s * 256 + tid;
    int row = c >> 3, kc = c & 7;
    int kcs = kc ^ (row & 7);          // pre-swizzled source chunk
    int tok = sel_idx[e * C_CAP + mt * 128 + row];
    ag[s] = xb + (size_t)tok * D_DIM + kcs * 8;
    int hcol = (row < 64) ? (nt * 64 + row) : (F_DIM + nt * 64 + (row - 64));
    bg[s] = w1t + ((size_t)e * 2 * F_DIM + hcol) * D_DIM + kcs * 8;
    lofs[s] = (unsigned)(s * 256 + wid * 64) * 16;
  }

  f32x4 zero = {0.f, 0.f, 0.f, 0.f};
  f32x4 acc[2][8];
  #pragma unroll
  for (int m = 0; m < 2; ++m)
    #pragma unroll
    for (int n = 0; n < 8; ++n) acc[m][n] = zero;

  int cl = lane & 15, rg = lane >> 4;
  int sw = cl & 7;

  // prologue: stage tile 0 into buffer 0
  #pragma unroll
  for (int s = 0; s < 4; ++s) {
    gld16(ag[s], (char*)As[0] + lofs[s]);
    gld16(bg[s], (char*)Bs[0] + lofs[s]);
  }
  __syncthreads();

  const int NK = D_DIM / 64;
  for (int kt = 0; kt < NK; ++kt) {
    int cur = kt & 1;
    if (kt + 1 < NK) {
      #pragma unroll
      for (int s = 0; s < 4; ++s) {
        gld16(ag[s] + (kt + 1) * 64, (char*)As[cur ^ 1] + lofs[s]);
        gld16(bg[s] + (kt + 1) * 64, (char*)Bs[cur ^ 1] + lofs[s]);
      }
    }
    #pragma unroll
    for (int kk = 0; kk < 64; kk += 32) {
      int cofs = (((kk >> 3) + rg) ^ sw) << 3;  // swizzled 16B-chunk offset
      bf16x8 a[2], b[8];
      #pragma unroll
      for (int m = 0; m < 2; ++m)
        a[m] = *(const bf16x8*)&As[cur][(wid * 32 + m * 16 + cl) * 64 + cofs];
      #pragma unroll
      for (int n = 0; n < 8; ++n)
        b[n] = *(const bf16x8*)&Bs[cur][(n * 16 + cl) * 64 + cofs];
      #pragma unroll
      for (int m = 0; m < 2; ++m)
        #pragma unroll
        for (int n = 0; n < 8; ++n)
          acc[m][n] = __builtin_amdgcn_mfma_f32_16x16x32_bf16(a[m], b[n], acc[m][n], 0, 0, 0);
    }
    __syncthreads();  // drains vmcnt(0): next buffer staged; all waves done with cur
  }

  // SwiGLU epilogue: act col j = h1[j] * silu(h2[j]); frag n pairs with frag n+4
  #pragma unroll
  for (int m = 0; m < 2; ++m) {
    #pragma unroll
    for (int n = 0; n < 4; ++n) {
      #pragma unroll
      for (int r = 0; r < 4; ++r) {
        int row = mt * 128 + wid * 32 + m * 16 + rg * 4 + r;
        int col = nt * 64 + n * 16 + cl;
        float h1 = acc[m][n][r];
        float h2 = acc[m][n + 4][r];
        float sg = h2 / (1.f + __expf(-h2));
        act[((size_t)e * C_CAP + row) * F_DIM + col] = f2bf(h1 * sg);
      }
    }
  }
}

// ---------------- GEMM2: out = act @ w2[e] * sel_w, scatter-add ----------------
// grid: e(16) x mt(16) x nt(4); tile 128 x 128; BK=64; same dbuf-prefetch scheme
__global__ __launch_bounds__(256) void gemm2_kernel(
    const unsigned short* __restrict__ act,   // [E][C][F] bf16
    const unsigned short* __restrict__ w2t,   // [E][D][F] bf16
    const int* __restrict__ sel_idx,
    const float* __restrict__ sel_w,
    float* __restrict__ out) {                // [T][D] fp32
  __shared__ __align__(16) unsigned short As[2][128 * 64];
  __shared__ __align__(16) unsigned short Bs[2][128 * 64];
  // XCD-bijective swizzle (grid 1024 = 8*128)
  int bid = (blockIdx.x & 7) * 128 + (blockIdx.x >> 3);
  int nt = bid & 3, mt = (bid >> 2) & 15, e = bid >> 6;
  int tid = threadIdx.x, lane = tid & 63, wid = tid >> 6;
  int wr = wid >> 1, wc = wid & 1;

  const unsigned short* ag[4];
  const unsigned short* bg[4];
  unsigned lofs[4];
  #pragma unroll
  for (int s = 0; s < 4; ++s) {
    int c = s * 256 + tid;
    int row = c >> 3, kc = c & 7;
    int kcs = kc ^ (row & 7);
    ag[s] = act + ((size_t)e * C_CAP + mt * 128 + row) * F_DIM + kcs * 8;
    int dcol = nt * 128 + row;
    bg[s] = w2t + ((size_t)e * D_DIM + dcol) * F_DIM + kcs * 8;
    lofs[s] = (unsigned)(s * 256 + wid * 64) * 16;
  }

  f32x4 zero = {0.f, 0.f, 0.f, 0.f};
  f32x4 acc[4][4];
  #pragma unroll
  for (int m = 0; m < 4; ++m)
    #pragma unroll
    for (int n = 0; n < 4; ++n) acc[m][n] = zero;

  int cl = lane & 15, rg = lane >> 4;
  int sw = cl & 7;

  #pragma unroll
  for (int s = 0; s < 4; ++s) {
    gld16(ag[s], (char*)As[0] + lofs[s]);
    gld16(bg[s], (char*)Bs[0] + lofs[s]);
  }
  __syncthreads();

  const int NK = F_DIM / 64;
  for (int kt = 0; kt < NK; ++kt) {
    int cur = kt & 1;
    if (kt + 1 < NK) {
      #pragma unroll
      for (int s = 0; s < 4; ++s) {
        gld16(ag[s] + (kt + 1) * 64, (char*)As[cur ^ 1] + lofs[s]);
        gld16(bg[s] + (kt + 1) * 64, (char*)Bs[cur ^ 1] + lofs[s]);
      }
    }
    #pragma unroll
    for (int kk = 0; kk < 64; kk += 32) {
      int cofs = (((kk >> 3) + rg) ^ sw) << 3;
      bf16x8 a[4], b[4];
      #pragma unroll
      for (int m = 0; m < 4; ++m)
        a[m] = *(const bf16x8*)&As[cur][(wr * 64 + m * 16 + cl) * 64 + cofs];
      #pragma unroll
      for (int n = 0; n < 4; ++n)
        b[n] = *(const bf16x8*)&Bs[cur][(wc * 64 + n * 16 + cl) * 64 + cofs];
      #pragma unroll
      for (int m = 0; m < 4; ++m)
        #pragma unroll
        for (int n = 0; n < 4; ++n)
          acc[m][n] = __builtin_amdgcn_mfma_f32_16x16x32_bf16(a[m], b[n], acc[m][n], 0, 0, 0);
    }
    __syncthreads();
  }

  #pragma unroll
  for (int m = 0; m < 4; ++m) {
    #pragma unroll
    for (int r = 0; r < 4; ++r) {
      int slot = mt * 128 + wr * 64 + m * 16 + rg * 4 + r;
      float wgt = sel_w[e * C_CAP + slot];
      int tok = sel_idx[e * C_CAP + slot];
      float* orow = out + (size_t)tok * D_DIM;
      #pragma unroll
      for (int n = 0; n < 4; ++n) {
        int col = nt * 128 + wc * 64 + n * 16 + cl;
        atomicAdd(&orow[col], acc[m][n][r] * wgt);
      }
    }
  }
}

// ---------------- launch ----------------
extern "C" void kernel_launch(void* const* d_in, const int* in_sizes, int n_in,
                              void* d_out, int out_size, void* d_ws, size_t ws_size,
                              hipStream_t stream) {
  const float* x  = (const float*)d_in[0];
  const float* wg = (const float*)d_in[1];
  const float* w1 = (const float*)d_in[2];
  const float* w2 = (const float*)d_in[3];
  float* out = (float*)d_out;

  char* ws = (char*)d_ws;
  size_t off = 0;
  auto carve = [&](size_t bytes) -> void* {
    void* p = ws + off;
    off += (bytes + 255) & ~(size_t)255;
    return p;
  };
  float* w_et            = (float*)carve((size_t)E_EXP * T_TOK * 4);
  float* phi             = (float*)carve(64);
  int* sel_i             = (int*)carve((size_t)E_EXP * C_CAP * 4);
  float* sel_wv          = (float*)carve((size_t)E_EXP * C_CAP * 4);
  unsigned short* xb     = (unsigned short*)carve((size_t)T_TOK * D_DIM * 2);
  unsigned short* w1t    = (unsigned short*)carve((size_t)E_EXP * 2 * F_DIM * D_DIM * 2);
  unsigned short* w2t    = (unsigned short*)carve((size_t)E_EXP * D_DIM * F_DIM * 2);
  unsigned short* actb   = (unsigned short*)carve((size_t)E_EXP * C_CAP * F_DIM * 2);
  if (off > ws_size) return;

  hipMemsetAsync(w_et, 0, (size_t)E_EXP * T_TOK * 4, stream);
  hipMemsetAsync(phi, 0, 64, stream);
  hipMemsetAsync(d_out, 0, (size_t)out_size * 4, stream);

  transpose_conv_kernel<<<dim3(2 * F_DIM / 32, D_DIM / 32, E_EXP), dim3(32, 8), 0, stream>>>(
      w1, w1t, D_DIM, 2 * F_DIM);
  transpose_conv_kernel<<<dim3(D_DIM / 32, F_DIM / 32, E_EXP), dim3(32, 8), 0, stream>>>(
      w2, w2t, F_DIM, D_DIM);
  gate_kernel<<<T_TOK / 16, 256, 0, stream>>>(x, wg, w_et, phi, xb);
  select_kernel<<<E_EXP, 1024, 0, stream>>>(w_et, sel_i, sel_wv);
  aux_kernel<<<1, 64, 0, stream>>>(phi, out + (size_t)T_TOK * D_DIM);
  gemm1_kernel<<<E_EXP * 16 * 16, 256, 0, stream>>>(xb, w1t, sel_i, actb);
  gemm2_kernel<<<E_EXP * 16 * 4, 256, 0, stream>>>(actb, w2t, sel_i, sel_wv, out);
}

// Round 4
// 336.370 us; speedup vs baseline: 1.3948x; 1.1891x over previous
//
#include <hip/hip_runtime.h>
#include <hip/hip_bf16.h>
#include <math.h>

#define T_TOK 32768
#define D_DIM 512
#define E_EXP 16
#define F_DIM 1024
#define C_CAP 2048

typedef __attribute__((ext_vector_type(8))) __bf16 bf16x8;
typedef __attribute__((ext_vector_type(4))) float f32x4;

__device__ __forceinline__ unsigned short f2bf(float f) {
  unsigned u = __float_as_uint(f);
  u += 0x7FFFu + ((u >> 16) & 1u);   // round-to-nearest-even
  return (unsigned short)(u >> 16);
}

__device__ __forceinline__ void gld16(const void* gptr, void* ldsptr) {
  __builtin_amdgcn_global_load_lds(
      (__attribute__((address_space(1))) void*)(void*)gptr,
      (__attribute__((address_space(3))) void*)ldsptr, 16, 0, 0);
}

// in: [E][R][Cc] fp32 -> out: [E][Cc][R] bf16 (transposed convert)
__global__ void transpose_conv_kernel(const float* __restrict__ in,
                                      unsigned short* __restrict__ out,
                                      int R, int Cc) {
  __shared__ float tile[32][33];
  int e = blockIdx.z;
  int r0 = blockIdx.y * 32, c0 = blockIdx.x * 32;
  const float* pin = in + (size_t)e * R * Cc;
  unsigned short* pout = out + (size_t)e * R * Cc;
  int tx = threadIdx.x, ty = threadIdx.y;  // 32 x 8
  #pragma unroll
  for (int i = 0; i < 32; i += 8)
    tile[ty + i][tx] = pin[(size_t)(r0 + ty + i) * Cc + c0 + tx];
  __syncthreads();
  #pragma unroll
  for (int i = 0; i < 32; i += 8)
    pout[(size_t)(c0 + ty + i) * R + r0 + tx] = f2bf(tile[tx][ty + i]);
}

// ---------------- gating (+ fused x -> bf16 conversion) ----------------
__global__ __launch_bounds__(256) void gate_kernel(
    const float* __restrict__ x, const float* __restrict__ wg,
    float* __restrict__ w_et, float* __restrict__ phi_sum,
    unsigned short* __restrict__ xb) {
  __shared__ float wgl[D_DIM * E_EXP];
  __shared__ float phil[E_EXP];
  int tid = threadIdx.x;
  for (int i = tid; i < D_DIM * E_EXP; i += 256) wgl[i] = wg[i];
  if (tid < E_EXP) phil[tid] = 0.f;
  __syncthreads();

  int g = tid >> 4;
  int e = tid & 15;
  int t = blockIdx.x * 16 + g;

  float acc = 0.f;
  const float* xr = x + (size_t)t * D_DIM;
  #pragma unroll 4
  for (int d = 0; d < D_DIM; d += 4) {
    float4 xv = *(const float4*)(xr + d);
    acc = fmaf(xv.x, wgl[(d + 0) * 16 + e], acc);
    acc = fmaf(xv.y, wgl[(d + 1) * 16 + e], acc);
    acc = fmaf(xv.z, wgl[(d + 2) * 16 + e], acc);
    acc = fmaf(xv.w, wgl[(d + 3) * 16 + e], acc);
  }

  // fused conversion: group lanes cover the row coalesced
  unsigned short* xrow = xb + (size_t)t * D_DIM;
  #pragma unroll
  for (int j = 0; j < 8; ++j) {
    int idx = j * 16 + e;
    float4 v = *(const float4*)(xr + idx * 4);
    ushort4 o;
    o.x = f2bf(v.x); o.y = f2bf(v.y); o.z = f2bf(v.z); o.w = f2bf(v.w);
    ((ushort4*)xrow)[idx] = o;
  }

  float m = acc;
  for (int off = 8; off; off >>= 1) m = fmaxf(m, __shfl_xor(m, off));
  float p = expf(acc - m);
  float s = p;
  for (int off = 8; off; off >>= 1) s += __shfl_xor(s, off);
  float score = p / s;
  atomicAdd(&phil[e], score);

  float v1 = score; int i1 = e;
  for (int off = 8; off; off >>= 1) {
    float ov = __shfl_xor(v1, off); int oi = __shfl_xor(i1, off);
    if (ov > v1 || (ov == v1 && oi < i1)) { v1 = ov; i1 = oi; }
  }
  float sc2 = (e == i1) ? -1.f : score;
  float v2 = sc2; int i2 = e;
  for (int off = 8; off; off >>= 1) {
    float ov = __shfl_xor(v2, off); int oi = __shfl_xor(i2, off);
    if (ov > v2 || (ov == v2 && oi < i2)) { v2 = ov; i2 = oi; }
  }
  if (e == 0) {
    w_et[(size_t)i1 * T_TOK + t] = v1;
    w_et[(size_t)i2 * T_TOK + t] = v2;
  }
  __syncthreads();
  if (tid < E_EXP) atomicAdd(&phi_sum[tid], phil[tid]);
}

__global__ void aux_kernel(const float* __restrict__ phi_sum, float* __restrict__ out_aux) {
  if (threadIdx.x == 0) {
    float s = 0.f;
    for (int e = 0; e < E_EXP; ++e) {
      float pm = phi_sum[e] / (float)T_TOK;
      s += pm * pm;
    }
    *out_aux = (float)E_EXP * s;
  }
}

// ============ top-C selection: 3-level radix (11/11/10), wide grids ============
// pass 0: bits 31..21; pass 1: bits 20..10; pass 2: bits 9..0.
template<int P>
__global__ __launch_bounds__(256) void s_hist(
    const float* __restrict__ w_et, unsigned* __restrict__ hist,
    const unsigned* __restrict__ prefix, const unsigned* __restrict__ done) {
  int c = blockIdx.x, e = blockIdx.y, tid = threadIdx.x;
  if (P > 0 && done[e]) return;
  __shared__ unsigned lh[2048];
  for (int i = tid; i < 2048; i += 256) lh[i] = 0;
  __syncthreads();
  const float* w = w_et + (size_t)e * T_TOK + c * 2048;
  unsigned pfx = (P > 0) ? prefix[e] : 0u;
  #pragma unroll
  for (int i = 0; i < 8; ++i) {
    unsigned b = __float_as_uint(w[i * 256 + tid]);
    if (P == 0) { if (b) atomicAdd(&lh[b >> 21], 1u); }
    else if (P == 1) { if ((b >> 21) == (pfx >> 21)) atomicAdd(&lh[(b >> 10) & 0x7FFu], 1u); }
    else { if ((b >> 10) == (pfx >> 10)) atomicAdd(&lh[b & 0x3FFu], 1u); }
  }
  __syncthreads();
  for (int i = tid; i < 2048; i += 256)
    if (lh[i]) atomicAdd(&hist[e * 2048 + i], lh[i]);
}

template<int P>
__global__ __launch_bounds__(1024) void s_pick(
    const unsigned* __restrict__ hist, unsigned* __restrict__ prefix,
    unsigned* __restrict__ krem, unsigned* __restrict__ done) {
  int tid = threadIdx.x, lane = tid & 63, e = tid >> 6;
  if (P > 0 && done[e]) return;
  const int BPL = (P == 2) ? 16 : 32;          // bins per lane (1024 or 2048 bins)
  const int SH = (P == 0) ? 21 : (P == 1) ? 10 : 0;
  const unsigned* h = hist + e * 2048;
  unsigned S = 0;
  for (int i = 0; i < BPL; ++i) S += h[lane * BPL + i];
  unsigned U = S;
  #pragma unroll
  for (int off = 1; off < 64; off <<= 1) {
    unsigned t = __shfl_down(U, off);
    if (lane + off < 64) U += t;
  }
  unsigned Unext = __shfl_down(U, 1);
  if (lane == 63) Unext = 0;
  unsigned k = (P == 0) ? (unsigned)C_CAP : krem[e];
  if (P == 0 && lane == 0) {
    if (U < k) { done[e] = 1; prefix[e] = 0; krem[e] = 0; }
    else done[e] = 0;
  }
  if (U >= k && Unext < k) {
    unsigned cum = Unext; int chosen = 0; unsigned knew = 0;
    for (int i = BPL - 1; i >= 0; --i) {
      unsigned hh = h[lane * BPL + i];
      if (cum + hh >= k) { chosen = lane * BPL + i; knew = k - cum; break; }
      cum += hh;
    }
    if (P == 0) prefix[e] = ((unsigned)chosen) << SH;
    else prefix[e] = prefix[e] | (((unsigned)chosen) << SH);
    krem[e] = knew;
  }
}

__global__ __launch_bounds__(256) void s_count(
    const float* __restrict__ w_et, const unsigned* __restrict__ prefix,
    unsigned* __restrict__ cnt) {
  int c = blockIdx.x, e = blockIdx.y, tid = threadIdx.x;
  unsigned thr = prefix[e];
  const uint4* up = (const uint4*)(w_et + (size_t)e * T_TOK + c * 2048 + tid * 8);
  uint4 va = up[0], vb = up[1];
  unsigned gt = 0, eq = 0;
  unsigned vals[8] = {va.x, va.y, va.z, va.w, vb.x, vb.y, vb.z, vb.w};
  #pragma unroll
  for (int i = 0; i < 8; ++i) {
    if (vals[i] > thr) gt++;
    else if (vals[i] == thr) eq++;
  }
  __shared__ unsigned sc[256];
  sc[tid] = (gt << 16) | eq;
  __syncthreads();
  for (int s = 128; s; s >>= 1) {
    if (tid < s) sc[tid] += sc[tid + s];
    __syncthreads();
  }
  if (tid == 0) cnt[e * 16 + c] = sc[0];
}

__global__ __launch_bounds__(64) void s_base(
    const unsigned* __restrict__ cnt, unsigned* __restrict__ gbase,
    unsigned* __restrict__ ebase, unsigned* __restrict__ gtt,
    unsigned* __restrict__ eqt) {
  int e = threadIdx.x;
  if (e >= 16) return;
  unsigned g = 0, q = 0;
  #pragma unroll
  for (int c = 0; c < 16; ++c) {
    unsigned p = cnt[e * 16 + c];
    gbase[e * 16 + c] = g;
    ebase[e * 16 + c] = q;
    g += p >> 16;
    q += p & 0xFFFFu;
  }
  gtt[e] = g;
  eqt[e] = (unsigned)C_CAP - g;   // g < C by radix construction
}

__global__ __launch_bounds__(256) void s_write(
    const float* __restrict__ w_et, const unsigned* __restrict__ prefix,
    const unsigned* __restrict__ gbase, const unsigned* __restrict__ ebase,
    const unsigned* __restrict__ gtt, const unsigned* __restrict__ eqt,
    int* __restrict__ sel_idx, float* __restrict__ sel_w) {
  int c = blockIdx.x, e = blockIdx.y, tid = threadIdx.x;
  unsigned thr = prefix[e];
  const uint4* up = (const uint4*)(w_et + (size_t)e * T_TOK + c * 2048 + tid * 8);
  uint4 va = up[0], vb = up[1];
  unsigned vals[8] = {va.x, va.y, va.z, va.w, vb.x, vb.y, vb.z, vb.w};
  unsigned gt = 0, eq = 0;
  #pragma unroll
  for (int i = 0; i < 8; ++i) {
    if (vals[i] > thr) gt++;
    else if (vals[i] == thr) eq++;
  }
  __shared__ unsigned sc[256];
  unsigned mine = (gt << 16) | eq;
  sc[tid] = mine;
  __syncthreads();
  // Hillis-Steele inclusive scan
  for (int off = 1; off < 256; off <<= 1) {
    unsigned add = (tid >= off) ? sc[tid - off] : 0u;
    __syncthreads();
    sc[tid] += add;
    __syncthreads();
  }
  unsigned excl = sc[tid] - mine;
  unsigned gpos = gbase[e * 16 + c] + (excl >> 16);
  unsigned qpos = ebase[e * 16 + c] + (excl & 0xFFFFu);
  unsigned gtotal = gtt[e], eqtake = eqt[e];
  int* si = sel_idx + (size_t)e * C_CAP;
  float* sw = sel_w + (size_t)e * C_CAP;
  int tokbase = c * 2048 + tid * 8;
  #pragma unroll
  for (int i = 0; i < 8; ++i) {
    unsigned b = vals[i];
    if (b > thr) {
      si[gpos] = tokbase + i; sw[gpos] = __uint_as_float(b); gpos++;
    } else if (b == thr && qpos < eqtake) {
      si[gtotal + qpos] = tokbase + i; sw[gtotal + qpos] = __uint_as_float(b); qpos++;
    }
  }
}

// ============ GEMMs: BK=32, 3-buffer 2-deep pipeline, counted vmcnt ============
// LDS chunk swizzle (64B rows = 4x16B chunks): lds_chunk = k_chunk ^ ((row>>1)&3)
// -> 16-lane b128 frag reads are 2-way (free). gld16 dest linear; source pre-swizzled.

#define PIPE_BARRIER() do { __builtin_amdgcn_s_barrier(); __builtin_amdgcn_sched_barrier(0); } while (0)

// ---- GEMM1: h = gather(x) @ w1[e], SwiGLU fused -> act bf16 ----
// grid e(16) x mt(16) x nt(16); tile 128 tok x (64 h1 + 64 h2); waves 2M x 2N
__global__ __launch_bounds__(256, 3) void gemm1_kernel(
    const unsigned short* __restrict__ xb,    // [T][D] bf16
    const unsigned short* __restrict__ w1t,   // [E][2F][D] bf16
    const int* __restrict__ sel_idx,          // [E][C]
    unsigned short* __restrict__ act) {       // [E][C][F] bf16
  __shared__ __align__(16) unsigned short As[3 * 4096];
  __shared__ __align__(16) unsigned short Bs[3 * 4096];
  int bid = (blockIdx.x & 7) * 512 + (blockIdx.x >> 3);
  int nt = bid & 15, mt = (bid >> 4) & 15, e = bid >> 8;
  int tid = threadIdx.x, lane = tid & 63, wid = tid >> 6;
  int wr = wid >> 1, wc = wid & 1;
  int cl = lane & 15, rg = lane >> 4;

  // staging: chunk c in [0,512): row=c>>2 (0..127), lds j=c&3, global chunk gk=j^((row>>1)&3)
  int c0 = tid, c1 = 256 + tid;
  int r0 = c0 >> 2, gk0 = (c0 & 3) ^ ((r0 >> 1) & 3);
  int r1 = c1 >> 2, gk1 = (c1 & 3) ^ ((r1 >> 1) & 3);
  int tok0 = sel_idx[e * C_CAP + mt * 128 + r0];
  int tok1 = sel_idx[e * C_CAP + mt * 128 + r1];
  const unsigned short* ag0 = xb + (size_t)tok0 * D_DIM + gk0 * 8;
  const unsigned short* ag1 = xb + (size_t)tok1 * D_DIM + gk1 * 8;
  int hcol0 = (r0 < 64) ? (nt * 64 + r0) : (F_DIM + nt * 64 + (r0 - 64));
  int hcol1 = (r1 < 64) ? (nt * 64 + r1) : (F_DIM + nt * 64 + (r1 - 64));
  const unsigned short* bg0 = w1t + ((size_t)e * 2 * F_DIM + hcol0) * D_DIM + gk0 * 8;
  const unsigned short* bg1 = w1t + ((size_t)e * 2 * F_DIM + hcol1) * D_DIM + gk1 * 8;
  char* Ab = (char*)As;
  char* Bb = (char*)Bs;

#define G1_STAGE(buf, kt) do { \
    gld16(ag0 + (kt) * 32, Ab + (buf) * 8192 + tid * 16); \
    gld16(ag1 + (kt) * 32, Ab + (buf) * 8192 + 4096 + tid * 16); \
    gld16(bg0 + (kt) * 32, Bb + (buf) * 8192 + tid * 16); \
    gld16(bg1 + (kt) * 32, Bb + (buf) * 8192 + 4096 + tid * 16); \
  } while (0)

  f32x4 zero = {0.f, 0.f, 0.f, 0.f};
  f32x4 acc[4][4];
  #pragma unroll
  for (int m = 0; m < 4; ++m)
    #pragma unroll
    for (int n = 0; n < 4; ++n) acc[m][n] = zero;

#define G1_COMPUTE(buf) do { \
    const unsigned short* Ap = As + (buf) * 4096; \
    const unsigned short* Bp = Bs + (buf) * 4096; \
    bf16x8 av[4], bv[4]; \
    _Pragma("unroll") \
    for (int m = 0; m < 4; ++m) { \
      int ra = wr * 64 + m * 16 + cl; \
      av[m] = *(const bf16x8*)&Ap[(ra * 4 + (rg ^ ((ra >> 1) & 3))) * 8]; \
    } \
    _Pragma("unroll") \
    for (int n = 0; n < 4; ++n) { \
      int rb = ((n < 2) ? (wc * 32 + n * 16) : (64 + wc * 32 + (n - 2) * 16)) + cl; \
      bv[n] = *(const bf16x8*)&Bp[(rb * 4 + (rg ^ ((rb >> 1) & 3))) * 8]; \
    } \
    _Pragma("unroll") \
    for (int m = 0; m < 4; ++m) \
      _Pragma("unroll") \
      for (int n = 0; n < 4; ++n) \
        acc[m][n] = __builtin_amdgcn_mfma_f32_16x16x32_bf16(av[m], bv[n], acc[m][n], 0, 0, 0); \
  } while (0)

  const int NK = D_DIM / 32;  // 16
  G1_STAGE(0, 0);
  G1_STAGE(1, 1);
  int bc = 0, bs = 2;
  for (int kt = 0; kt < NK - 1; ++kt) {
    asm volatile("s_waitcnt vmcnt(4)" ::: "memory");
    PIPE_BARRIER();
    if (kt + 2 < NK) { G1_STAGE(bs, kt + 2); bs = (bs == 2) ? 0 : bs + 1; }
    __builtin_amdgcn_sched_barrier(0);
    G1_COMPUTE(bc);
    bc = (bc == 2) ? 0 : bc + 1;
  }
  asm volatile("s_waitcnt vmcnt(0)" ::: "memory");
  PIPE_BARRIER();
  G1_COMPUTE(bc);

  // SwiGLU epilogue: n in {0,1} = h1 frags, n+2 = matching h2 frags
  #pragma unroll
  for (int m = 0; m < 4; ++m) {
    #pragma unroll
    for (int n = 0; n < 2; ++n) {
      #pragma unroll
      for (int r = 0; r < 4; ++r) {
        int row = mt * 128 + wr * 64 + m * 16 + rg * 4 + r;
        int col = nt * 64 + wc * 32 + n * 16 + cl;
        float h1 = acc[m][n][r];
        float h2 = acc[m][n + 2][r];
        float sg = h2 / (1.f + __expf(-h2));
        act[((size_t)e * C_CAP + row) * F_DIM + col] = f2bf(h1 * sg);
      }
    }
  }
#undef G1_STAGE
#undef G1_COMPUTE
}

// ---- GEMM2: out = act @ w2[e] * sel_w, scatter-add ----
// grid e(16) x mt(16) x nt(4); tile 128 x 128; waves 2M x 2N
__global__ __launch_bounds__(256, 3) void gemm2_kernel(
    const unsigned short* __restrict__ act,   // [E][C][F] bf16
    const unsigned short* __restrict__ w2t,   // [E][D][F] bf16
    const int* __restrict__ sel_idx,
    const float* __restrict__ sel_w,
    float* __restrict__ out) {                // [T][D] fp32
  __shared__ __align__(16) unsigned short As[3 * 4096];
  __shared__ __align__(16) unsigned short Bs[3 * 4096];
  int bid = (blockIdx.x & 7) * 128 + (blockIdx.x >> 3);
  int nt = bid & 3, mt = (bid >> 2) & 15, e = bid >> 6;
  int tid = threadIdx.x, lane = tid & 63, wid = tid >> 6;
  int wr = wid >> 1, wc = wid & 1;
  int cl = lane & 15, rg = lane >> 4;

  int c0 = tid, c1 = 256 + tid;
  int r0 = c0 >> 2, gk0 = (c0 & 3) ^ ((r0 >> 1) & 3);
  int r1 = c1 >> 2, gk1 = (c1 & 3) ^ ((r1 >> 1) & 3);
  const unsigned short* ag0 = act + ((size_t)e * C_CAP + mt * 128 + r0) * F_DIM + gk0 * 8;
  const unsigned short* ag1 = act + ((size_t)e * C_CAP + mt * 128 + r1) * F_DIM + gk1 * 8;
  const unsigned short* bg0 = w2t + ((size_t)e * D_DIM + nt * 128 + r0) * F_DIM + gk0 * 8;
  const unsigned short* bg1 = w2t + ((size_t)e * D_DIM + nt * 128 + r1) * F_DIM + gk1 * 8;
  char* Ab = (char*)As;
  char* Bb = (char*)Bs;

#define G2_STAGE(buf, kt) do { \
    gld16(ag0 + (kt) * 32, Ab + (buf) * 8192 + tid * 16); \
    gld16(ag1 + (kt) * 32, Ab + (buf) * 8192 + 4096 + tid * 16); \
    gld16(bg0 + (kt) * 32, Bb + (buf) * 8192 + tid * 16); \
    gld16(bg1 + (kt) * 32, Bb + (buf) * 8192 + 4096 + tid * 16); \
  } while (0)

  f32x4 zero = {0.f, 0.f, 0.f, 0.f};
  f32x4 acc[4][4];
  #pragma unroll
  for (int m = 0; m < 4; ++m)
    #pragma unroll
    for (int n = 0; n < 4; ++n) acc[m][n] = zero;

#define G2_COMPUTE(buf) do { \
    const unsigned short* Ap = As + (buf) * 4096; \
    const unsigned short* Bp = Bs + (buf) * 4096; \
    bf16x8 av[4], bv[4]; \
    _Pragma("unroll") \
    for (int m = 0; m < 4; ++m) { \
      int ra = wr * 64 + m * 16 + cl; \
      av[m] = *(const bf16x8*)&Ap[(ra * 4 + (rg ^ ((ra >> 1) & 3))) * 8]; \
    } \
    _Pragma("unroll") \
    for (int n = 0; n < 4; ++n) { \
      int rb = wc * 64 + n * 16 + cl; \
      bv[n] = *(const bf16x8*)&Bp[(rb * 4 + (rg ^ ((rb >> 1) & 3))) * 8]; \
    } \
    _Pragma("unroll") \
    for (int m = 0; m < 4; ++m) \
      _Pragma("unroll") \
      for (int n = 0; n < 4; ++n) \
        acc[m][n] = __builtin_amdgcn_mfma_f32_16x16x32_bf16(av[m], bv[n], acc[m][n], 0, 0, 0); \
  } while (0)

  const int NK = F_DIM / 32;  // 32
  G2_STAGE(0, 0);
  G2_STAGE(1, 1);
  int bc = 0, bs = 2;
  for (int kt = 0; kt < NK - 1; ++kt) {
    asm volatile("s_waitcnt vmcnt(4)" ::: "memory");
    PIPE_BARRIER();
    if (kt + 2 < NK) { G2_STAGE(bs, kt + 2); bs = (bs == 2) ? 0 : bs + 1; }
    __builtin_amdgcn_sched_barrier(0);
    G2_COMPUTE(bc);
    bc = (bc == 2) ? 0 : bc + 1;
  }
  asm volatile("s_waitcnt vmcnt(0)" ::: "memory");
  PIPE_BARRIER();
  G2_COMPUTE(bc);

  #pragma unroll
  for (int m = 0; m < 4; ++m) {
    #pragma unroll
    for (int r = 0; r < 4; ++r) {
      int slot = mt * 128 + wr * 64 + m * 16 + rg * 4 + r;
      float wgt = sel_w[e * C_CAP + slot];
      int tok = sel_idx[e * C_CAP + slot];
      float* orow = out + (size_t)tok * D_DIM;
      #pragma unroll
      for (int n = 0; n < 4; ++n) {
        int col = nt * 128 + wc * 64 + n * 16 + cl;
        atomicAdd(&orow[col], acc[m][n][r] * wgt);
      }
    }
  }
#undef G2_STAGE
#undef G2_COMPUTE
}

// ---------------- launch ----------------
extern "C" void kernel_launch(void* const* d_in, const int* in_sizes, int n_in,
                              void* d_out, int out_size, void* d_ws, size_t ws_size,
                              hipStream_t stream) {
  const float* x  = (const float*)d_in[0];
  const float* wg = (const float*)d_in[1];
  const float* w1 = (const float*)d_in[2];
  const float* w2 = (const float*)d_in[3];
  float* out = (float*)d_out;

  char* ws = (char*)d_ws;
  size_t off = 0;
  auto carve = [&](size_t bytes) -> void* {
    void* p = ws + off;
    off += (bytes + 255) & ~(size_t)255;
    return p;
  };
  float* w_et            = (float*)carve((size_t)E_EXP * T_TOK * 4);
  float* phi             = (float*)carve(64);
  int* sel_i             = (int*)carve((size_t)E_EXP * C_CAP * 4);
  float* sel_wv          = (float*)carve((size_t)E_EXP * C_CAP * 4);
  unsigned short* xb     = (unsigned short*)carve((size_t)T_TOK * D_DIM * 2);
  unsigned short* w1t    = (unsigned short*)carve((size_t)E_EXP * 2 * F_DIM * D_DIM * 2);
  unsigned short* w2t    = (unsigned short*)carve((size_t)E_EXP * D_DIM * F_DIM * 2);
  unsigned short* actb   = (unsigned short*)carve((size_t)E_EXP * C_CAP * F_DIM * 2);
  unsigned* hist0        = (unsigned*)carve((size_t)E_EXP * 2048 * 4);
  unsigned* hist1        = (unsigned*)carve((size_t)E_EXP * 2048 * 4);
  unsigned* hist2        = (unsigned*)carve((size_t)E_EXP * 2048 * 4);
  unsigned* prefix       = (unsigned*)carve(64 * 4);
  unsigned* krem         = (unsigned*)carve(64 * 4);
  unsigned* done         = (unsigned*)carve(64 * 4);
  unsigned* cnt          = (unsigned*)carve(256 * 4);
  unsigned* gbase        = (unsigned*)carve(256 * 4);
  unsigned* ebase        = (unsigned*)carve(256 * 4);
  unsigned* gtt          = (unsigned*)carve(64 * 4);
  unsigned* eqt          = (unsigned*)carve(64 * 4);
  if (off > ws_size) return;

  hipMemsetAsync(w_et, 0, (size_t)E_EXP * T_TOK * 4, stream);
  hipMemsetAsync(phi, 0, 64, stream);
  hipMemsetAsync(hist0, 0, (size_t)E_EXP * 2048 * 4 * 3, stream);  // hist0..2 contiguous
  hipMemsetAsync(d_out, 0, (size_t)out_size * 4, stream);

  transpose_conv_kernel<<<dim3(2 * F_DIM / 32, D_DIM / 32, E_EXP), dim3(32, 8), 0, stream>>>(
      w1, w1t, D_DIM, 2 * F_DIM);
  transpose_conv_kernel<<<dim3(D_DIM / 32, F_DIM / 32, E_EXP), dim3(32, 8), 0, stream>>>(
      w2, w2t, F_DIM, D_DIM);
  gate_kernel<<<T_TOK / 16, 256, 0, stream>>>(x, wg, w_et, phi, xb);

  s_hist<0><<<dim3(16, 16), 256, 0, stream>>>(w_et, hist0, prefix, done);
  s_pick<0><<<1, 1024, 0, stream>>>(hist0, prefix, krem, done);
  s_hist<1><<<dim3(16, 16), 256, 0, stream>>>(w_et, hist1, prefix, done);
  s_pick<1><<<1, 1024, 0, stream>>>(hist1, prefix, krem, done);
  s_hist<2><<<dim3(16, 16), 256, 0, stream>>>(w_et, hist2, prefix, done);
  s_pick<2><<<1, 1024, 0, stream>>>(hist2, prefix, krem, done);
  s_count<<<dim3(16, 16), 256, 0, stream>>>(w_et, prefix, cnt);
  s_base<<<1, 64, 0, stream>>>(cnt, gbase, ebase, gtt, eqt);
  s_write<<<dim3(16, 16), 256, 0, stream>>>(w_et, prefix, gbase, ebase, gtt, eqt,
                                            sel_i, sel_wv);

  aux_kernel<<<1, 64, 0, stream>>>(phi, out + (size_t)T_TOK * D_DIM);
  gemm1_kernel<<<E_EXP * 16 * 16, 256, 0, stream>>>(xb, w1t, sel_i, actb);
  gemm2_kernel<<<E_EXP * 16 * 4, 256, 0, stream>>>(actb, w2t, sel_i, sel_wv, out);
}